// Round 12
// baseline (95.742 us; speedup 1.0000x reference)
//
#include <hip/hip_runtime.h>
#include <hip/hip_bf16.h>

#define NB   32
#define GDIM 307
#define IN_ROW 309
#define IN_B  (13*309)
#define NROWS (NB*GDIM)          // 9824
#define MPAD  9856               // 77*128

typedef __attribute__((ext_vector_type(8))) short bf16x8;
typedef __attribute__((ext_vector_type(4))) float f32x4;

__device__ __forceinline__ void async_copy16(const void* g, void* l) {
  __builtin_amdgcn_global_load_lds(
      (const __attribute__((address_space(1))) void*)g,
      (__attribute__((address_space(3))) void*)l, 16, 0, 0);
}

// Bijective XCD-chunk swizzle (m204): blocks with consecutive new-ids land on
// the SAME XCD (dispatch round-robin bid%8), so A-tile sharers co-locate.
__device__ __forceinline__ int xcd_swz(int bid, int nwg) {
  int q = nwg >> 3, r = nwg & 7;
  int xcd = bid & 7, i = bid >> 3;
  int base = (xcd < r) ? xcd*(q+1) : r*(q+1) + (xcd-r)*q;
  return base + i;
}

// ============ MFMA GEMM core (128x64 tile, BK=64, XOR-swizzled LDS, gload_lds w16)
__device__ __forceinline__ void mgemm_body(
    const __hip_bfloat16* __restrict__ A, int ldA,
    const __hip_bfloat16* __restrict__ Bt, int ldB,
    const float* bias, void* C, int ldC, long Czoff,
    int M, int N, int kt0, int kt1, int act, int outbf,
    char* smem, int m0, int n0) {
  const int tid = threadIdx.x;
  const int w = tid >> 6, lane = tid & 63;
  f32x4 acc[4][2];
  #pragma unroll
  for (int i=0;i<4;i++)
    #pragma unroll
    for (int j=0;j<2;j++) acc[i][j] = (f32x4){0.f,0.f,0.f,0.f};
  const int wm = (w>>1)*64, wn = (w&1)*32;
  const int l15 = lane & 15, lhi = lane >> 4;

  for (int kt = kt0; kt < kt1; ++kt) {
    const int k0 = kt*64;
    #pragma unroll
    for (int i=0;i<4;i++) {
      int c = w*256 + i*64 + lane;
      int row = c >> 3, j = c & 7;
      int jg = j ^ (row & 7);
      async_copy16(A + (size_t)(m0+row)*ldA + k0 + jg*8, smem + (w*256 + i*64)*16);
    }
    #pragma unroll
    for (int i=0;i<2;i++) {
      int c = w*128 + i*64 + lane;
      int row = c >> 3, j = c & 7;
      int jg = j ^ (row & 7);
      async_copy16(Bt + (size_t)(n0+row)*ldB + k0 + jg*8, smem + 16384 + (w*128 + i*64)*16);
    }
    __syncthreads();
    #pragma unroll
    for (int kk=0;kk<2;kk++) {
      bf16x8 af[4], bfr[2];
      #pragma unroll
      for (int fi=0; fi<4; fi++) {
        int row = wm + fi*16 + l15;
        af[fi] = *(const bf16x8*)(smem + row*128 + (((kk<<2)+lhi) ^ (row&7))*16);
      }
      #pragma unroll
      for (int fj=0; fj<2; fj++) {
        int n = wn + fj*16 + l15;
        bfr[fj] = *(const bf16x8*)(smem + 16384 + n*128 + (((kk<<2)+lhi) ^ (n&7))*16);
      }
      #pragma unroll
      for (int fi=0;fi<4;fi++)
        #pragma unroll
        for (int fj=0;fj<2;fj++)
          acc[fi][fj] = __builtin_amdgcn_mfma_f32_16x16x32_bf16(af[fi], bfr[fj], acc[fi][fj], 0, 0, 0);
    }
    __syncthreads();
  }

  #pragma unroll
  for (int fi=0;fi<4;fi++) {
    int row0 = m0 + wm + fi*16 + lhi*4;
    #pragma unroll
    for (int fj=0;fj<2;fj++) {
      int col = n0 + wn + fj*16 + l15;
      if (col < N) {
        float bv = bias ? bias[col] : 0.f;
        #pragma unroll
        for (int r=0;r<4;r++) {
          int row = row0 + r;
          if (row < M) {
            float v = acc[fi][fj][r] + bv;
            if (act) v = fmaxf(v, 0.f);
            if (outbf)
              ((__hip_bfloat16*)C)[(size_t)row*ldC + col] = __float2bfloat16(v);
            else
              ((float*)C + Czoff)[(size_t)row*ldC + col] = v;
          }
        }
      }
    }
  }
}

// ============ transpose tile helper: dst[n][k] = bf16(src[k][n]), zero-pad OOB
__device__ __forceinline__ void tr_tile(const float* src, __hip_bfloat16* dst,
    int sK, int sN, int dR, int ldD, int bx, int by, char* smem, int tid) {
  float (*t)[65] = (float(*)[65])smem;
  int k0 = bx*64, n0 = by*64;
  int tx = tid & 63, ty = tid >> 6;
  for (int r = ty; r < 64; r += 4) {
    int k = k0 + r, n = n0 + tx;
    t[r][tx] = (k < sK && n < sN) ? src[(size_t)k*sN + n] : 0.f;
  }
  __syncthreads();
  for (int r = ty; r < 64; r += 4) {
    int n = n0 + r, k = k0 + tx;
    if (n < dR && k < ldD) dst[(size_t)n*ldD + k] = __float2bfloat16(t[tx][r]);
  }
}

// ============ F1 (critical-path only): prep [0,384) + l0 [384,692) + tr{Wse1,Wte1} [692,764)
__global__ __launch_bounds__(256) void k_f1(
    const float* __restrict__ inp, const float* __restrict__ dws,
    const float* __restrict__ cw, const float* __restrict__ cb,
    float* __restrict__ A_pre, float* __restrict__ Cp,
    const float* se1, const float* te1,
    __hip_bfloat16* Wse1, __hip_bfloat16* Wte1,
    const float* se0, const float* seb0, const float* te0, const float* teb0,
    __hip_bfloat16* __restrict__ hA_se, __hip_bfloat16* __restrict__ hA_te) {
  __shared__ alignas(16) char smem[23040];
  int bid = blockIdx.x, tid = threadIdx.x;
  if (bid < 384) {
    int b = bid / 12, t = bid - b*12;
    float* scw = (float*)smem;
    float* scb = scw + 32;
    if (tid < 32) { scw[tid] = cw[tid]; scb[tid] = cb[tid]; }
    __syncthreads();
    int date = (int)inp[b*IN_B + 1];
    const float* dw = dws + (size_t)date * 147456 + t*12288;
    for (int r = tid; r < 384; r += 256) {
      float sA = 0.f, sC = 0.f;
      #pragma unroll
      for (int e = 0; e < 32; e++) {
        float v = dw[e*384 + r];
        sA += scw[e] * v;
        sC += scb[e] * v;
      }
      A_pre[(b*12 + t)*384 + r] = sA;
      Cp[(b*12 + t)*384 + r]    = sC;
    }
  } else if (bid < 692) {
    int idx = bid - 384;
    int z = idx / 154, mt = idx - z*154;
    int r0 = mt*64;
    const float* w0 = z ? te0 : se0;
    const float* b0 = z ? teb0 : seb0;
    __hip_bfloat16* H = z ? hA_te : hA_se;
    float* sw = (float*)smem;          // 4608
    float* sb = sw + 4608;             // 384
    float* sx = sb + 384;              // 768
    for (int i = tid; i < 4608; i += 256) sw[i] = w0[i];
    for (int i = tid; i < 384; i += 256) sb[i] = b0[i];
    for (int v = tid; v < 768; v += 256) {
      int r = v / 12, t = v - r*12;
      int row = r0 + r;
      float xv = 0.f;
      if (row < NROWS) {
        int b = row / GDIM, g = row - b*GDIM;
        xv = inp[b*IN_B + (1+t)*IN_ROW + 2 + g];
      }
      sx[v] = xv;
    }
    __syncthreads();
    for (int c = tid; c < 384; c += 256) {
      float wv[12];
      #pragma unroll
      for (int t = 0; t < 12; t++) wv[t] = sw[t*384 + c];
      float bv = sb[c];
      for (int r = 0; r < 64; r++) {
        int row = r0 + r;
        if (row >= NROWS) break;
        float acc = bv;
        #pragma unroll
        for (int t = 0; t < 12; t++) acc += sx[r*12+t] * wv[t];
        H[(size_t)row*384 + c] = __float2bfloat16(fmaxf(acc, 0.f));
      }
    }
  } else {
    int s = bid - 692;
    int q = s / 36, u = s % 36;
    tr_tile(q ? te1 : se1, q ? Wte1 : Wse1, 384, 384, 384, 384, u % 6, u / 6, smem, tid);
  }
}

// ============ F2: L1 GEMM se/te [0,924, XCD-swz) + tr-rest [924,1784) + xln(6g) [1784,3448)
__global__ __launch_bounds__(256) void k_f2(
    const __hip_bfloat16* __restrict__ hA_se, const __hip_bfloat16* __restrict__ hA_te,
    const __hip_bfloat16* __restrict__ Wse1, const __hip_bfloat16* __restrict__ Wte1,
    const float* __restrict__ seb1, const float* __restrict__ teb1,
    __hip_bfloat16* __restrict__ hB_se, __hip_bfloat16* __restrict__ hB_te,
    const float* __restrict__ inp, const float* __restrict__ dbs,
    const float* __restrict__ A_pre, const float* __restrict__ Cp,
    const float* __restrict__ gamma, const float* __restrict__ beta,
    __hip_bfloat16* __restrict__ xlnT, __hip_bfloat16* __restrict__ xg,
    const float* se2, const float* te2, const float* se3, const float* te3,
    const float* g2g, const float* tgw,
    __hip_bfloat16* Wse2, __hip_bfloat16* Wte2, __hip_bfloat16* Wse3,
    __hip_bfloat16* Wte3, __hip_bfloat16* Wgt, __hip_bfloat16* Wtg) {
  __shared__ alignas(16) char smem[29472];   // <32KB -> 5 blocks/CU
  int bid = blockIdx.x, tid = threadIdx.x;
  if (bid < 924) {
    int s = xcd_swz(bid, 924);           // same-m blocks -> same XCD (A reuse in L2)
    int z = s / 462, rem = s - z*462;
    mgemm_body(z ? hA_te : hA_se, 384, z ? Wte1 : Wse1, 384,
               z ? teb1 : seb1, z ? hB_te : hB_se, 384, 0,
               NROWS, 384, 0, 6, 0, 1, smem, (rem/6)*128, (rem%6)*64);
  } else if (bid < 1784) {
    int s = bid - 924;
    if (s < 770) {
      tr_tile(tgw, Wtg, 9824, 307, 320, 9856, s % 154, s / 154, smem, tid);
    } else if (s < 842) {
      int q = (s-770) / 36, u = (s-770) % 36;
      tr_tile(q ? te2 : se2, q ? Wte2 : Wse2, 384, 384, 384, 384, u % 6, u / 6, smem, tid);
    } else {
      int q = (s-842) / 6, u = (s-842) % 6;
      const float* src = q==0?se3 : q==1?te3 : g2g;
      __hip_bfloat16* dst = q==0?Wse3 : q==1?Wte3 : Wgt;
      tr_tile(src, dst, 384, 12, 64, 384, u, 0, smem, tid);
    }
  } else {
    // xln: 6 g per block; 32 b x 52 chunks
    int idx = bid - 1784;
    int b = idx / 52, gc = idx - b*52;
    int g0 = gc*6, ng = min(6, GDIM - g0);
    float* sA  = (float*)smem;          // 4608
    float* sxb = sA + 4608;             // 2304 (6x384)
    float* sCs = sxb + 2304;            // 384
    float* sx3 = sCs + 384;             // 72
    int date = (int)inp[b*IN_B + 1];
    for (int v = tid; v < 4608; v += 256) sA[v] = A_pre[b*4608 + v];
    for (int e = tid; e < 384; e += 256) {
      float s = 0.f;
      #pragma unroll
      for (int t = 0; t < 12; t++) s += Cp[b*4608 + t*384 + e];
      sCs[e] = s;
    }
    if (tid < ng*12) {
      int gl = tid / 12, t = tid - gl*12;
      sx3[tid] = inp[b*IN_B + (1+t)*IN_ROW + 2 + g0 + gl];
    }
    if (gc == 51) {   // last chunk: zero xlnT K-pad cols [9824,9856) for this b
      for (int v = tid; v < 384; v += 256) {
        int j = v >> 5, c = v & 31;
        xlnT[(size_t)(b*12+j)*9856 + 9824 + c] = __float2bfloat16(0.f);
      }
    }
    __syncthreads();
    for (int o = tid; o < ng*384; o += 256) {
      int gl = o / 384, e = o - gl*384;
      float acc = sCs[e] + dbs[(size_t)date*117888 + (g0+gl)*384 + e];
      #pragma unroll
      for (int t = 0; t < 12; t++) acc += sx3[gl*12+t] * sA[t*384 + e];
      sxb[gl*384 + e] = acc;
    }
    __syncthreads();
    if (tid < ng*32) {
      int gl = tid >> 5, i = tid & 31;
      const float* xb = sxb + gl*384 + i*12;
      float m = 0.f;
      #pragma unroll
      for (int q = 0; q < 12; q++) m += xb[q];
      m *= (1.f/12.f);
      float v = 0.f;
      #pragma unroll
      for (int q = 0; q < 12; q++) { float d = xb[q] - m; v += d*d; }
      v *= (1.f/12.f);
      float rs = rsqrtf(v + 1e-3f);
      int g = g0 + gl;
      #pragma unroll
      for (int j = 0; j < 12; j++) {
        float y = (xb[j] - m) * rs * gamma[j] + beta[j];
        y = (y >= 0.f) ? y : 0.3f*y;
        __hip_bfloat16 yb = __float2bfloat16(y);
        xlnT[(size_t)(b*12 + j)*9856 + g*32 + i] = yb;
        int q2 = j*GDIM + g;
        int gq = q2 / 12, tq = q2 - gq*12;
        xg[(size_t)(b*GDIM + gq)*384 + tq*32 + i] = yb;
      }
    }
  }
}

// ============ F3: L2 GEMM se/te [0,924, swz) + tg splitK z=8 [924,1044, swz) + gt [1044,1121)
__global__ __launch_bounds__(256) void k_f3(
    const __hip_bfloat16* __restrict__ hB_se, const __hip_bfloat16* __restrict__ hB_te,
    const __hip_bfloat16* __restrict__ Wse2, const __hip_bfloat16* __restrict__ Wte2,
    const float* __restrict__ seb2, const float* __restrict__ teb2,
    __hip_bfloat16* __restrict__ hA_se, __hip_bfloat16* __restrict__ hA_te,
    const __hip_bfloat16* __restrict__ xlnT, const __hip_bfloat16* __restrict__ Wtg,
    float* __restrict__ tgp,
    const __hip_bfloat16* __restrict__ xg, const __hip_bfloat16* __restrict__ Wgt,
    float* __restrict__ gtv) {
  __shared__ alignas(16) char smem[24576];
  int bid = blockIdx.x;
  if (bid < 924) {
    int s = xcd_swz(bid, 924);
    int z = s / 462, rem = s - z*462;
    mgemm_body(z ? hB_te : hB_se, 384, z ? Wte2 : Wse2, 384,
               z ? teb2 : seb2, z ? hA_te : hA_se, 384, 0,
               NROWS, 384, 0, 6, 1, 1, smem, (rem/6)*128, (rem%6)*64);
  } else if (bid < 1044) {
    int s = xcd_swz(bid - 924, 120);     // z == XCD: each XCD owns one K-chunk
    int z = s / 15, rem = s - z*15;
    int n0 = (rem % 5)*64, m0 = (rem / 5)*128;
    int kt0 = z*20, kt1 = min(154, kt0 + 20);
    mgemm_body(xlnT, 9856, Wtg, 9856, nullptr, tgp, 320, (long)z*122880,
               384, 320, kt0, kt1, 0, 0, smem, m0, n0);
  } else {
    int m0 = (bid - 1044)*128;
    mgemm_body(xg, 384, Wgt, 384, nullptr, gtv, 12, 0,
               NROWS, 12, 0, 6, 0, 0, smem, m0, 0);
  }
}

// ============ F4: L3 GEMM se/te [0,154) + tgred(8) [154,274)
__global__ __launch_bounds__(256) void k_f4(
    const __hip_bfloat16* __restrict__ hA_se, const __hip_bfloat16* __restrict__ hA_te,
    const __hip_bfloat16* __restrict__ Wse3, const __hip_bfloat16* __restrict__ Wte3,
    const float* __restrict__ seb3, const float* __restrict__ teb3,
    float* __restrict__ x1, float* __restrict__ x2,
    const float* __restrict__ tgp, float* __restrict__ tgv) {
  __shared__ alignas(16) char smem[24576];
  int bid = blockIdx.x;
  if (bid < 154) {
    int z = bid / 77, m0 = (bid - z*77)*128;
    mgemm_body(z ? hA_te : hA_se, 384, z ? Wte3 : Wse3, 384,
               z ? teb3 : seb3, z ? x2 : x1, 12, 0,
               NROWS, 12, 0, 6, 0, 0, smem, m0, 0);
  } else {
    int base = (bid - 154) * 1024;
    #pragma unroll
    for (int q = 0; q < 4; q++) {
      int gid = base + q*256 + threadIdx.x;
      float s = 0.f;
      #pragma unroll
      for (int z = 0; z < 8; z++) s += tgp[(size_t)z*122880 + gid];
      tgv[gid] = s;
    }
  }
}

// ============ F5: gates + fully_w + scale
__global__ __launch_bounds__(256) void k_final(const float* __restrict__ tgv,
    const float* __restrict__ gt, const float* __restrict__ x1,
    const float* __restrict__ x2, const float* __restrict__ fw,
    float* __restrict__ out) {
  __shared__ float w[288];
  for (int idx = threadIdx.x; idx < 288; idx += 256) w[idx] = fw[idx];
  __syncthreads();
  int gid = blockIdx.x*256 + threadIdx.x;
  if (gid >= NROWS) return;
  int b = gid / GDIM, g = gid - b*GDIM;
  float g1[12], g2[12];
  #pragma unroll
  for (int n = 0; n < 12; n++) {
    float tv  = tgv[(size_t)(b*12+n)*320 + g];
    float x1v = x1[(size_t)gid*12 + n];
    float gv  = gt[(size_t)gid*12 + n];
    float x2v = x2[(size_t)gid*12 + n];
    float s1 = 1.f/(1.f + __expf(-tv));
    float s2 = 1.f/(1.f + __expf(-gv));
    g1[n] = (tv + x1v)*s1;
    g2[n] = (gv + x2v)*s2;
  }
  #pragma unroll
  for (int o = 0; o < 12; o++) {
    float acc = 0.f;
    #pragma unroll
    for (int n = 0; n < 12; n++)
      acc += g1[n]*w[n*12+o] + g2[n]*w[(12+n)*12+o];
    out[(size_t)(b*12+o)*GDIM + g] = acc*50.f + 60.f;
  }
}

extern "C" void kernel_launch(void* const* d_in, const int* in_sizes, int n_in,
                              void* d_out, int out_size, void* d_ws, size_t ws_size,
                              hipStream_t stream) {
  const float* inp    = (const float*)d_in[0];
  const float* cw     = (const float*)d_in[1];
  const float* cb     = (const float*)d_in[2];
  const float* dws    = (const float*)d_in[3];
  const float* dbs    = (const float*)d_in[4];
  const float* ln_g   = (const float*)d_in[5];
  const float* ln_b   = (const float*)d_in[6];
  const float* tge2tg = (const float*)d_in[7];
  const float* gte2gt = (const float*)d_in[8];
  const float* fullyw = (const float*)d_in[9];
  const float* se[8];
  const float* te[8];
  for (int i = 0; i < 8; i++) { se[i] = (const float*)d_in[10+i]; te[i] = (const float*)d_in[18+i]; }
  float* out = (float*)d_out;

  // ---- workspace carve (~60 MB, no aliasing) ----
  char* base = (char*)d_ws;
  size_t off = 0;
  auto alloc = [&](size_t bytes) { char* r = base + off; off += (bytes + 255) & ~(size_t)255; return r; };
  float* A_pre = (float*)alloc(147456*4);
  float* Cp    = (float*)alloc(147456*4);
  float* x1    = (float*)alloc(117888*4);
  float* x2    = (float*)alloc(117888*4);
  float* gtv   = (float*)alloc(117888*4);
  float* tgv   = (float*)alloc(122880*4);
  float* tgp   = (float*)alloc((size_t)8*122880*4);
  __hip_bfloat16* hA_se = (__hip_bfloat16*)alloc((size_t)MPAD*384*2);
  __hip_bfloat16* hA_te = (__hip_bfloat16*)alloc((size_t)MPAD*384*2);
  __hip_bfloat16* hB_se = (__hip_bfloat16*)alloc((size_t)MPAD*384*2);
  __hip_bfloat16* hB_te = (__hip_bfloat16*)alloc((size_t)MPAD*384*2);
  __hip_bfloat16* xlnT  = (__hip_bfloat16*)alloc((size_t)384*9856*2);
  __hip_bfloat16* xg    = (__hip_bfloat16*)alloc((size_t)MPAD*384*2);
  __hip_bfloat16* Wse1 = (__hip_bfloat16*)alloc(147456*2);
  __hip_bfloat16* Wse2 = (__hip_bfloat16*)alloc(147456*2);
  __hip_bfloat16* Wte1 = (__hip_bfloat16*)alloc(147456*2);
  __hip_bfloat16* Wte2 = (__hip_bfloat16*)alloc(147456*2);
  __hip_bfloat16* Wse3 = (__hip_bfloat16*)alloc(24576*2);
  __hip_bfloat16* Wte3 = (__hip_bfloat16*)alloc(24576*2);
  __hip_bfloat16* Wgt  = (__hip_bfloat16*)alloc(24576*2);
  __hip_bfloat16* Wtg  = (__hip_bfloat16*)alloc((size_t)320*9856*2);

  // F1: prep + layer-0 + Wse1/Wte1 transposes (critical path for F2 only)
  k_f1<<<764, 256, 0, stream>>>(inp, dws, cw, cb, A_pre, Cp,
      se[2], te[2], Wse1, Wte1,
      se[0], se[1], te[0], te[1], hA_se, hA_te);

  // F2: L1 GEMMs (XCD-swizzled) + remaining transposes + xln(6g)
  k_f2<<<3448, 256, 0, stream>>>(hA_se, hA_te, Wse1, Wte1, se[3], te[3],
      hB_se, hB_te, inp, dbs, A_pre, Cp, ln_g, ln_b, xlnT, xg,
      se[4], te[4], se[6], te[6], gte2gt, tge2tg,
      Wse2, Wte2, Wse3, Wte3, Wgt, Wtg);

  // F3: L2 GEMMs (XCD-swizzled) + tg split-K z=8 (XCD==z) + gt
  k_f3<<<1121, 256, 0, stream>>>(hB_se, hB_te, Wse2, Wte2, se[5], te[5],
      hA_se, hA_te, xlnT, Wtg, tgp, xg, Wgt, gtv);

  // F4: L3 GEMMs + tg partial reduction (z=8)
  k_f4<<<274, 256, 0, stream>>>(hA_se, hA_te, Wse3, Wte3, se[7], te[7], x1, x2, tgp, tgv);

  // F5: gates + output
  k_final<<<39, 256, 0, stream>>>(tgv, gtv, x1, x2, fullyw, out);
}

// Round 13
// 93.018 us; speedup vs baseline: 1.0293x; 1.0293x over previous
//
#include <hip/hip_runtime.h>
#include <hip/hip_bf16.h>

#define NB   32
#define GDIM 307
#define IN_ROW 309
#define IN_B  (13*309)
#define NROWS (NB*GDIM)          // 9824
#define MPAD  9856               // 77*128

typedef __attribute__((ext_vector_type(8))) short bf16x8;
typedef __attribute__((ext_vector_type(4))) float f32x4;

__device__ __forceinline__ void async_copy16(const void* g, void* l) {
  __builtin_amdgcn_global_load_lds(
      (const __attribute__((address_space(1))) void*)g,
      (__attribute__((address_space(3))) void*)l, 16, 0, 0);
}

// Bijective XCD-chunk swizzle (m204): blocks with consecutive new-ids land on
// the SAME XCD (dispatch round-robin bid%8), so A-tile sharers co-locate.
__device__ __forceinline__ int xcd_swz(int bid, int nwg) {
  int q = nwg >> 3, r = nwg & 7;
  int xcd = bid & 7, i = bid >> 3;
  int base = (xcd < r) ? xcd*(q+1) : r*(q+1) + (xcd-r)*q;
  return base + i;
}

// ============ MFMA GEMM core (128x64 tile, BK=64, XOR-swizzled LDS, gload_lds w16)
__device__ __forceinline__ void mgemm_body(
    const __hip_bfloat16* __restrict__ A, int ldA,
    const __hip_bfloat16* __restrict__ Bt, int ldB,
    const float* bias, void* C, int ldC, long Czoff,
    int M, int N, int kt0, int kt1, int act, int outbf,
    char* smem, int m0, int n0) {
  const int tid = threadIdx.x;
  const int w = tid >> 6, lane = tid & 63;
  f32x4 acc[4][2];
  #pragma unroll
  for (int i=0;i<4;i++)
    #pragma unroll
    for (int j=0;j<2;j++) acc[i][j] = (f32x4){0.f,0.f,0.f,0.f};
  const int wm = (w>>1)*64, wn = (w&1)*32;
  const int l15 = lane & 15, lhi = lane >> 4;

  for (int kt = kt0; kt < kt1; ++kt) {
    const int k0 = kt*64;
    #pragma unroll
    for (int i=0;i<4;i++) {
      int c = w*256 + i*64 + lane;
      int row = c >> 3, j = c & 7;
      int jg = j ^ (row & 7);
      async_copy16(A + (size_t)(m0+row)*ldA + k0 + jg*8, smem + (w*256 + i*64)*16);
    }
    #pragma unroll
    for (int i=0;i<2;i++) {
      int c = w*128 + i*64 + lane;
      int row = c >> 3, j = c & 7;
      int jg = j ^ (row & 7);
      async_copy16(Bt + (size_t)(n0+row)*ldB + k0 + jg*8, smem + 16384 + (w*128 + i*64)*16);
    }
    __syncthreads();
    #pragma unroll
    for (int kk=0;kk<2;kk++) {
      bf16x8 af[4], bfr[2];
      #pragma unroll
      for (int fi=0; fi<4; fi++) {
        int row = wm + fi*16 + l15;
        af[fi] = *(const bf16x8*)(smem + row*128 + (((kk<<2)+lhi) ^ (row&7))*16);
      }
      #pragma unroll
      for (int fj=0; fj<2; fj++) {
        int n = wn + fj*16 + l15;
        bfr[fj] = *(const bf16x8*)(smem + 16384 + n*128 + (((kk<<2)+lhi) ^ (n&7))*16);
      }
      #pragma unroll
      for (int fi=0;fi<4;fi++)
        #pragma unroll
        for (int fj=0;fj<2;fj++)
          acc[fi][fj] = __builtin_amdgcn_mfma_f32_16x16x32_bf16(af[fi], bfr[fj], acc[fi][fj], 0, 0, 0);
    }
    __syncthreads();
  }

  #pragma unroll
  for (int fi=0;fi<4;fi++) {
    int row0 = m0 + wm + fi*16 + lhi*4;
    #pragma unroll
    for (int fj=0;fj<2;fj++) {
      int col = n0 + wn + fj*16 + l15;
      if (col < N) {
        float bv = bias ? bias[col] : 0.f;
        #pragma unroll
        for (int r=0;r<4;r++) {
          int row = row0 + r;
          if (row < M) {
            float v = acc[fi][fj][r] + bv;
            if (act) v = fmaxf(v, 0.f);
            if (outbf)
              ((__hip_bfloat16*)C)[(size_t)row*ldC + col] = __float2bfloat16(v);
            else
              ((float*)C + Czoff)[(size_t)row*ldC + col] = v;
          }
        }
      }
    }
  }
}

// ============ transpose tile helper: dst[n][k] = bf16(src[k][n]), zero-pad OOB
__device__ __forceinline__ void tr_tile(const float* src, __hip_bfloat16* dst,
    int sK, int sN, int dR, int ldD, int bx, int by, char* smem, int tid) {
  float (*t)[65] = (float(*)[65])smem;
  int k0 = bx*64, n0 = by*64;
  int tx = tid & 63, ty = tid >> 6;
  for (int r = ty; r < 64; r += 4) {
    int k = k0 + r, n = n0 + tx;
    t[r][tx] = (k < sK && n < sN) ? src[(size_t)k*sN + n] : 0.f;
  }
  __syncthreads();
  for (int r = ty; r < 64; r += 4) {
    int n = n0 + r, k = k0 + tx;
    if (n < dR && k < ldD) dst[(size_t)n*ldD + k] = __float2bfloat16(t[tx][r]);
  }
}

// ============ F1 (critical-path only): prep [0,384) + l0 [384,692) + tr{Wse1,Wte1} [692,764)
__global__ __launch_bounds__(256) void k_f1(
    const float* __restrict__ inp, const float* __restrict__ dws,
    const float* __restrict__ cw, const float* __restrict__ cb,
    float* __restrict__ A_pre, float* __restrict__ Cp,
    const float* se1, const float* te1,
    __hip_bfloat16* Wse1, __hip_bfloat16* Wte1,
    const float* se0, const float* seb0, const float* te0, const float* teb0,
    __hip_bfloat16* __restrict__ hA_se, __hip_bfloat16* __restrict__ hA_te) {
  __shared__ alignas(16) char smem[23040];
  int bid = blockIdx.x, tid = threadIdx.x;
  if (bid < 384) {
    int b = bid / 12, t = bid - b*12;
    float* scw = (float*)smem;
    float* scb = scw + 32;
    if (tid < 32) { scw[tid] = cw[tid]; scb[tid] = cb[tid]; }
    __syncthreads();
    int date = (int)inp[b*IN_B + 1];
    const float* dw = dws + (size_t)date * 147456 + t*12288;
    for (int r = tid; r < 384; r += 256) {
      float sA = 0.f, sC = 0.f;
      #pragma unroll
      for (int e = 0; e < 32; e++) {
        float v = dw[e*384 + r];
        sA += scw[e] * v;
        sC += scb[e] * v;
      }
      A_pre[(b*12 + t)*384 + r] = sA;
      Cp[(b*12 + t)*384 + r]    = sC;
    }
  } else if (bid < 692) {
    int idx = bid - 384;
    int z = idx / 154, mt = idx - z*154;
    int r0 = mt*64;
    const float* w0 = z ? te0 : se0;
    const float* b0 = z ? teb0 : seb0;
    __hip_bfloat16* H = z ? hA_te : hA_se;
    float* sw = (float*)smem;          // 4608
    float* sb = sw + 4608;             // 384
    float* sx = sb + 384;              // 768
    for (int i = tid; i < 4608; i += 256) sw[i] = w0[i];
    for (int i = tid; i < 384; i += 256) sb[i] = b0[i];
    for (int v = tid; v < 768; v += 256) {
      int r = v / 12, t = v - r*12;
      int row = r0 + r;
      float xv = 0.f;
      if (row < NROWS) {
        int b = row / GDIM, g = row - b*GDIM;
        xv = inp[b*IN_B + (1+t)*IN_ROW + 2 + g];
      }
      sx[v] = xv;
    }
    __syncthreads();
    for (int c = tid; c < 384; c += 256) {
      float wv[12];
      #pragma unroll
      for (int t = 0; t < 12; t++) wv[t] = sw[t*384 + c];
      float bv = sb[c];
      for (int r = 0; r < 64; r++) {
        int row = r0 + r;
        if (row >= NROWS) break;
        float acc = bv;
        #pragma unroll
        for (int t = 0; t < 12; t++) acc += sx[r*12+t] * wv[t];
        H[(size_t)row*384 + c] = __float2bfloat16(fmaxf(acc, 0.f));
      }
    }
  } else {
    int s = bid - 692;
    int q = s / 36, u = s % 36;
    tr_tile(q ? te1 : se1, q ? Wte1 : Wse1, 384, 384, 384, 384, u % 6, u / 6, smem, tid);
  }
}

// ============ F2: L1 GEMM se/te [0,924, XCD-swz) + tr-rest [924,1784) + xln [1784,3032)
__global__ __launch_bounds__(256) void k_f2(
    const __hip_bfloat16* __restrict__ hA_se, const __hip_bfloat16* __restrict__ hA_te,
    const __hip_bfloat16* __restrict__ Wse1, const __hip_bfloat16* __restrict__ Wte1,
    const float* __restrict__ seb1, const float* __restrict__ teb1,
    __hip_bfloat16* __restrict__ hB_se, __hip_bfloat16* __restrict__ hB_te,
    const float* __restrict__ inp, const float* __restrict__ dbs,
    const float* __restrict__ A_pre, const float* __restrict__ Cp,
    const float* __restrict__ gamma, const float* __restrict__ beta,
    __hip_bfloat16* __restrict__ xlnT, __hip_bfloat16* __restrict__ xg,
    const float* se2, const float* te2, const float* se3, const float* te3,
    const float* g2g, const float* tgw,
    __hip_bfloat16* Wse2, __hip_bfloat16* Wte2, __hip_bfloat16* Wse3,
    __hip_bfloat16* Wte3, __hip_bfloat16* Wgt, __hip_bfloat16* Wtg) {
  __shared__ alignas(16) char smem[32640];
  int bid = blockIdx.x, tid = threadIdx.x;
  if (bid < 924) {
    int s = xcd_swz(bid, 924);           // same-m blocks -> same XCD (A reuse in L2)
    int z = s / 462, rem = s - z*462;
    mgemm_body(z ? hA_te : hA_se, 384, z ? Wte1 : Wse1, 384,
               z ? teb1 : seb1, z ? hB_te : hB_se, 384, 0,
               NROWS, 384, 0, 6, 0, 1, smem, (rem/6)*128, (rem%6)*64);
  } else if (bid < 1784) {
    int s = bid - 924;
    if (s < 770) {
      tr_tile(tgw, Wtg, 9824, 307, 320, 9856, s % 154, s / 154, smem, tid);
    } else if (s < 842) {
      int q = (s-770) / 36, u = (s-770) % 36;
      tr_tile(q ? te2 : se2, q ? Wte2 : Wse2, 384, 384, 384, 384, u % 6, u / 6, smem, tid);
    } else {
      int q = (s-842) / 6, u = (s-842) % 6;
      const float* src = q==0?se3 : q==1?te3 : g2g;
      __hip_bfloat16* dst = q==0?Wse3 : q==1?Wte3 : Wgt;
      tr_tile(src, dst, 384, 12, 64, 384, u, 0, smem, tid);
    }
  } else {
    // xln: 8 g per block; 32 b x 39 chunks
    int idx = bid - 1784;
    int b = idx / 39, gc = idx - b*39;
    int g0 = gc*8, ng = min(8, GDIM - g0);
    float* sA  = (float*)smem;          // 4608
    float* sxb = sA + 4608;             // 3072 (8x384)
    float* sCs = sxb + 3072;            // 384
    float* sx3 = sCs + 384;             // 96
    int date = (int)inp[b*IN_B + 1];
    for (int v = tid; v < 4608; v += 256) sA[v] = A_pre[b*4608 + v];
    for (int e = tid; e < 384; e += 256) {
      float s = 0.f;
      #pragma unroll
      for (int t = 0; t < 12; t++) s += Cp[b*4608 + t*384 + e];
      sCs[e] = s;
    }
    if (tid < ng*12) {
      int gl = tid / 12, t = tid - gl*12;
      sx3[tid] = inp[b*IN_B + (1+t)*IN_ROW + 2 + g0 + gl];
    }
    if (gc == 38) {
      for (int v = tid; v < 384; v += 256) {
        int j = v >> 5, c = v & 31;
        xlnT[(size_t)(b*12+j)*9856 + 9824 + c] = __float2bfloat16(0.f);
      }
    }
    __syncthreads();
    for (int o = tid; o < ng*384; o += 256) {
      int gl = o / 384, e = o - gl*384;
      float acc = sCs[e] + dbs[(size_t)date*117888 + (g0+gl)*384 + e];
      #pragma unroll
      for (int t = 0; t < 12; t++) acc += sx3[gl*12+t] * sA[t*384 + e];
      sxb[gl*384 + e] = acc;
    }
    __syncthreads();
    if (tid < ng*32) {
      int gl = tid >> 5, i = tid & 31;
      const float* xb = sxb + gl*384 + i*12;
      float m = 0.f;
      #pragma unroll
      for (int q = 0; q < 12; q++) m += xb[q];
      m *= (1.f/12.f);
      float v = 0.f;
      #pragma unroll
      for (int q = 0; q < 12; q++) { float d = xb[q] - m; v += d*d; }
      v *= (1.f/12.f);
      float rs = rsqrtf(v + 1e-3f);
      int g = g0 + gl;
      #pragma unroll
      for (int j = 0; j < 12; j++) {
        float y = (xb[j] - m) * rs * gamma[j] + beta[j];
        y = (y >= 0.f) ? y : 0.3f*y;
        __hip_bfloat16 yb = __float2bfloat16(y);
        xlnT[(size_t)(b*12 + j)*9856 + g*32 + i] = yb;
        int q2 = j*GDIM + g;
        int gq = q2 / 12, tq = q2 - gq*12;
        xg[(size_t)(b*GDIM + gq)*384 + tq*32 + i] = yb;
      }
    }
  }
}

// ============ F3: L2 GEMM se/te [0,924, XCD-swz) + tg splitK [924,1164, XCD-swz) + gt [1164,1241)
__global__ __launch_bounds__(256) void k_f3(
    const __hip_bfloat16* __restrict__ hB_se, const __hip_bfloat16* __restrict__ hB_te,
    const __hip_bfloat16* __restrict__ Wse2, const __hip_bfloat16* __restrict__ Wte2,
    const float* __restrict__ seb2, const float* __restrict__ teb2,
    __hip_bfloat16* __restrict__ hA_se, __hip_bfloat16* __restrict__ hA_te,
    const __hip_bfloat16* __restrict__ xlnT, const __hip_bfloat16* __restrict__ Wtg,
    float* __restrict__ tgp,
    const __hip_bfloat16* __restrict__ xg, const __hip_bfloat16* __restrict__ Wgt,
    float* __restrict__ gtv) {
  __shared__ alignas(16) char smem[24576];
  int bid = blockIdx.x;
  if (bid < 924) {
    int s = xcd_swz(bid, 924);
    int z = s / 462, rem = s - z*462;
    mgemm_body(z ? hB_te : hB_se, 384, z ? Wte2 : Wse2, 384,
               z ? teb2 : seb2, z ? hA_te : hA_se, 384, 0,
               NROWS, 384, 0, 6, 1, 1, smem, (rem/6)*128, (rem%6)*64);
  } else if (bid < 1164) {
    int s = xcd_swz(bid - 924, 240);     // same-(z,m) blocks -> same XCD (xlnT reuse)
    int z = s / 15, rem = s - z*15;
    int n0 = (rem % 5)*64, m0 = (rem / 5)*128;
    int kt0 = z*10, kt1 = min(154, kt0 + 10);
    mgemm_body(xlnT, 9856, Wtg, 9856, nullptr, tgp, 320, (long)z*122880,
               384, 320, kt0, kt1, 0, 0, smem, m0, n0);
  } else {
    int m0 = (bid - 1164)*128;
    mgemm_body(xg, 384, Wgt, 384, nullptr, gtv, 12, 0,
               NROWS, 12, 0, 6, 0, 0, smem, m0, 0);
  }
}

// ============ F4: L3 GEMM se/te [0,154) + tgred [154,274)
__global__ __launch_bounds__(256) void k_f4(
    const __hip_bfloat16* __restrict__ hA_se, const __hip_bfloat16* __restrict__ hA_te,
    const __hip_bfloat16* __restrict__ Wse3, const __hip_bfloat16* __restrict__ Wte3,
    const float* __restrict__ seb3, const float* __restrict__ teb3,
    float* __restrict__ x1, float* __restrict__ x2,
    const float* __restrict__ tgp, float* __restrict__ tgv) {
  __shared__ alignas(16) char smem[24576];
  int bid = blockIdx.x;
  if (bid < 154) {
    int z = bid / 77, m0 = (bid - z*77)*128;
    mgemm_body(z ? hA_te : hA_se, 384, z ? Wte3 : Wse3, 384,
               z ? teb3 : seb3, z ? x2 : x1, 12, 0,
               NROWS, 12, 0, 6, 0, 0, smem, m0, 0);
  } else {
    int base = (bid - 154) * 1024;
    #pragma unroll
    for (int q = 0; q < 4; q++) {
      int gid = base + q*256 + threadIdx.x;
      float s = 0.f;
      #pragma unroll
      for (int z = 0; z < 16; z++) s += tgp[(size_t)z*122880 + gid];
      tgv[gid] = s;
    }
  }
}

// ============ F5: gates + fully_w + scale
__global__ __launch_bounds__(256) void k_final(const float* __restrict__ tgv,
    const float* __restrict__ gt, const float* __restrict__ x1,
    const float* __restrict__ x2, const float* __restrict__ fw,
    float* __restrict__ out) {
  __shared__ float w[288];
  for (int idx = threadIdx.x; idx < 288; idx += 256) w[idx] = fw[idx];
  __syncthreads();
  int gid = blockIdx.x*256 + threadIdx.x;
  if (gid >= NROWS) return;
  int b = gid / GDIM, g = gid - b*GDIM;
  float g1[12], g2[12];
  #pragma unroll
  for (int n = 0; n < 12; n++) {
    float tv  = tgv[(size_t)(b*12+n)*320 + g];
    float x1v = x1[(size_t)gid*12 + n];
    float gv  = gt[(size_t)gid*12 + n];
    float x2v = x2[(size_t)gid*12 + n];
    float s1 = 1.f/(1.f + __expf(-tv));
    float s2 = 1.f/(1.f + __expf(-gv));
    g1[n] = (tv + x1v)*s1;
    g2[n] = (gv + x2v)*s2;
  }
  #pragma unroll
  for (int o = 0; o < 12; o++) {
    float acc = 0.f;
    #pragma unroll
    for (int n = 0; n < 12; n++)
      acc += g1[n]*w[n*12+o] + g2[n]*w[(12+n)*12+o];
    out[(size_t)(b*12+o)*GDIM + g] = acc*50.f + 60.f;
  }
}

extern "C" void kernel_launch(void* const* d_in, const int* in_sizes, int n_in,
                              void* d_out, int out_size, void* d_ws, size_t ws_size,
                              hipStream_t stream) {
  const float* inp    = (const float*)d_in[0];
  const float* cw     = (const float*)d_in[1];
  const float* cb     = (const float*)d_in[2];
  const float* dws    = (const float*)d_in[3];
  const float* dbs    = (const float*)d_in[4];
  const float* ln_g   = (const float*)d_in[5];
  const float* ln_b   = (const float*)d_in[6];
  const float* tge2tg = (const float*)d_in[7];
  const float* gte2gt = (const float*)d_in[8];
  const float* fullyw = (const float*)d_in[9];
  const float* se[8];
  const float* te[8];
  for (int i = 0; i < 8; i++) { se[i] = (const float*)d_in[10+i]; te[i] = (const float*)d_in[18+i]; }
  float* out = (float*)d_out;

  // ---- workspace carve (~64 MB, no aliasing) ----
  char* base = (char*)d_ws;
  size_t off = 0;
  auto alloc = [&](size_t bytes) { char* r = base + off; off += (bytes + 255) & ~(size_t)255; return r; };
  float* A_pre = (float*)alloc(147456*4);
  float* Cp    = (float*)alloc(147456*4);
  float* x1    = (float*)alloc(117888*4);
  float* x2    = (float*)alloc(117888*4);
  float* gtv   = (float*)alloc(117888*4);
  float* tgv   = (float*)alloc(122880*4);
  float* tgp   = (float*)alloc((size_t)16*122880*4);
  __hip_bfloat16* hA_se = (__hip_bfloat16*)alloc((size_t)MPAD*384*2);
  __hip_bfloat16* hA_te = (__hip_bfloat16*)alloc((size_t)MPAD*384*2);
  __hip_bfloat16* hB_se = (__hip_bfloat16*)alloc((size_t)MPAD*384*2);
  __hip_bfloat16* hB_te = (__hip_bfloat16*)alloc((size_t)MPAD*384*2);
  __hip_bfloat16* xlnT  = (__hip_bfloat16*)alloc((size_t)384*9856*2);
  __hip_bfloat16* xg    = (__hip_bfloat16*)alloc((size_t)MPAD*384*2);
  __hip_bfloat16* Wse1 = (__hip_bfloat16*)alloc(147456*2);
  __hip_bfloat16* Wse2 = (__hip_bfloat16*)alloc(147456*2);
  __hip_bfloat16* Wte1 = (__hip_bfloat16*)alloc(147456*2);
  __hip_bfloat16* Wte2 = (__hip_bfloat16*)alloc(147456*2);
  __hip_bfloat16* Wse3 = (__hip_bfloat16*)alloc(24576*2);
  __hip_bfloat16* Wte3 = (__hip_bfloat16*)alloc(24576*2);
  __hip_bfloat16* Wgt  = (__hip_bfloat16*)alloc(24576*2);
  __hip_bfloat16* Wtg  = (__hip_bfloat16*)alloc((size_t)320*9856*2);

  // F1: prep + layer-0 + Wse1/Wte1 transposes (critical path for F2 only)
  k_f1<<<764, 256, 0, stream>>>(inp, dws, cw, cb, A_pre, Cp,
      se[2], te[2], Wse1, Wte1,
      se[0], se[1], te[0], te[1], hA_se, hA_te);

  // F2: L1 GEMMs (XCD-swizzled) + remaining transposes + xln
  k_f2<<<3032, 256, 0, stream>>>(hA_se, hA_te, Wse1, Wte1, se[3], te[3],
      hB_se, hB_te, inp, dbs, A_pre, Cp, ln_g, ln_b, xlnT, xg,
      se[4], te[4], se[6], te[6], gte2gt, tge2tg,
      Wse2, Wte2, Wse3, Wte3, Wgt, Wtg);

  // F3: L2 GEMMs (XCD-swizzled) + tg split-K (XCD-swizzled) + gt
  k_f3<<<1241, 256, 0, stream>>>(hB_se, hB_te, Wse2, Wte2, se[5], te[5],
      hA_se, hA_te, xlnT, Wtg, tgp, xg, Wgt, gtv);

  // F4: L3 GEMMs + tg partial reduction
  k_f4<<<274, 256, 0, stream>>>(hA_se, hA_te, Wse3, Wte3, se[7], te[7], x1, x2, tgp, tgv);

  // F5: gates + output
  k_final<<<39, 256, 0, stream>>>(tgv, gtv, x1, x2, fullyw, out);
}

// Round 14
// 92.466 us; speedup vs baseline: 1.0354x; 1.0060x over previous
//
#include <hip/hip_runtime.h>
#include <hip/hip_bf16.h>

#define NB   32
#define GDIM 307
#define IN_ROW 309
#define IN_B  (13*309)
#define NROWS (NB*GDIM)          // 9824
#define MPAD  9856               // 77*128

typedef __attribute__((ext_vector_type(8))) short bf16x8;
typedef __attribute__((ext_vector_type(4))) float f32x4;

__device__ __forceinline__ void async_copy16(const void* g, void* l) {
  __builtin_amdgcn_global_load_lds(
      (const __attribute__((address_space(1))) void*)g,
      (__attribute__((address_space(3))) void*)l, 16, 0, 0);
}

// Bijective XCD-chunk swizzle (m204): blocks with consecutive new-ids land on
// the SAME XCD (dispatch round-robin bid%8), so data-sharing blocks co-locate.
__device__ __forceinline__ int xcd_swz(int bid, int nwg) {
  int q = nwg >> 3, r = nwg & 7;
  int xcd = bid & 7, i = bid >> 3;
  int base = (xcd < r) ? xcd*(q+1) : r*(q+1) + (xcd-r)*q;
  return base + i;
}

// ============ MFMA GEMM core (128x64 tile, BK=64, XOR-swizzled LDS, gload_lds w16)
__device__ __forceinline__ void mgemm_body(
    const __hip_bfloat16* __restrict__ A, int ldA,
    const __hip_bfloat16* __restrict__ Bt, int ldB,
    const float* bias, void* C, int ldC, long Czoff,
    int M, int N, int kt0, int kt1, int act, int outbf,
    char* smem, int m0, int n0) {
  const int tid = threadIdx.x;
  const int w = tid >> 6, lane = tid & 63;
  f32x4 acc[4][2];
  #pragma unroll
  for (int i=0;i<4;i++)
    #pragma unroll
    for (int j=0;j<2;j++) acc[i][j] = (f32x4){0.f,0.f,0.f,0.f};
  const int wm = (w>>1)*64, wn = (w&1)*32;
  const int l15 = lane & 15, lhi = lane >> 4;

  for (int kt = kt0; kt < kt1; ++kt) {
    const int k0 = kt*64;
    #pragma unroll
    for (int i=0;i<4;i++) {
      int c = w*256 + i*64 + lane;
      int row = c >> 3, j = c & 7;
      int jg = j ^ (row & 7);
      async_copy16(A + (size_t)(m0+row)*ldA + k0 + jg*8, smem + (w*256 + i*64)*16);
    }
    #pragma unroll
    for (int i=0;i<2;i++) {
      int c = w*128 + i*64 + lane;
      int row = c >> 3, j = c & 7;
      int jg = j ^ (row & 7);
      async_copy16(Bt + (size_t)(n0+row)*ldB + k0 + jg*8, smem + 16384 + (w*128 + i*64)*16);
    }
    __syncthreads();
    #pragma unroll
    for (int kk=0;kk<2;kk++) {
      bf16x8 af[4], bfr[2];
      #pragma unroll
      for (int fi=0; fi<4; fi++) {
        int row = wm + fi*16 + l15;
        af[fi] = *(const bf16x8*)(smem + row*128 + (((kk<<2)+lhi) ^ (row&7))*16);
      }
      #pragma unroll
      for (int fj=0; fj<2; fj++) {
        int n = wn + fj*16 + l15;
        bfr[fj] = *(const bf16x8*)(smem + 16384 + n*128 + (((kk<<2)+lhi) ^ (n&7))*16);
      }
      #pragma unroll
      for (int fi=0;fi<4;fi++)
        #pragma unroll
        for (int fj=0;fj<2;fj++)
          acc[fi][fj] = __builtin_amdgcn_mfma_f32_16x16x32_bf16(af[fi], bfr[fj], acc[fi][fj], 0, 0, 0);
    }
    __syncthreads();
  }

  #pragma unroll
  for (int fi=0;fi<4;fi++) {
    int row0 = m0 + wm + fi*16 + lhi*4;
    #pragma unroll
    for (int fj=0;fj<2;fj++) {
      int col = n0 + wn + fj*16 + l15;
      if (col < N) {
        float bv = bias ? bias[col] : 0.f;
        #pragma unroll
        for (int r=0;r<4;r++) {
          int row = row0 + r;
          if (row < M) {
            float v = acc[fi][fj][r] + bv;
            if (act) v = fmaxf(v, 0.f);
            if (outbf)
              ((__hip_bfloat16*)C)[(size_t)row*ldC + col] = __float2bfloat16(v);
            else
              ((float*)C + Czoff)[(size_t)row*ldC + col] = v;
          }
        }
      }
    }
  }
}

// ============ transpose tile helper: dst[n][k] = bf16(src[k][n]), zero-pad OOB
__device__ __forceinline__ void tr_tile(const float* src, __hip_bfloat16* dst,
    int sK, int sN, int dR, int ldD, int bx, int by, char* smem, int tid) {
  float (*t)[65] = (float(*)[65])smem;
  int k0 = bx*64, n0 = by*64;
  int tx = tid & 63, ty = tid >> 6;
  for (int r = ty; r < 64; r += 4) {
    int k = k0 + r, n = n0 + tx;
    t[r][tx] = (k < sK && n < sN) ? src[(size_t)k*sN + n] : 0.f;
  }
  __syncthreads();
  for (int r = ty; r < 64; r += 4) {
    int n = n0 + r, k = k0 + tx;
    if (n < dR && k < ldD) dst[(size_t)n*ldD + k] = __float2bfloat16(t[tx][r]);
  }
}

// ============ F1 (critical-path only): prep [0,384) + l0 [384,692) + tr{Wse1,Wte1} [692,764)
__global__ __launch_bounds__(256) void k_f1(
    const float* __restrict__ inp, const float* __restrict__ dws,
    const float* __restrict__ cw, const float* __restrict__ cb,
    float* __restrict__ A_pre, float* __restrict__ Cp,
    const float* se1, const float* te1,
    __hip_bfloat16* Wse1, __hip_bfloat16* Wte1,
    const float* se0, const float* seb0, const float* te0, const float* teb0,
    __hip_bfloat16* __restrict__ hA_se, __hip_bfloat16* __restrict__ hA_te) {
  __shared__ alignas(16) char smem[23040];
  int bid = blockIdx.x, tid = threadIdx.x;
  if (bid < 384) {
    int b = bid / 12, t = bid - b*12;
    float* scw = (float*)smem;
    float* scb = scw + 32;
    if (tid < 32) { scw[tid] = cw[tid]; scb[tid] = cb[tid]; }
    __syncthreads();
    int date = (int)inp[b*IN_B + 1];
    const float* dw = dws + (size_t)date * 147456 + t*12288;
    for (int r = tid; r < 384; r += 256) {
      float sA = 0.f, sC = 0.f;
      #pragma unroll
      for (int e = 0; e < 32; e++) {
        float v = dw[e*384 + r];
        sA += scw[e] * v;
        sC += scb[e] * v;
      }
      A_pre[(b*12 + t)*384 + r] = sA;
      Cp[(b*12 + t)*384 + r]    = sC;
    }
  } else if (bid < 692) {
    int idx = bid - 384;
    int z = idx / 154, mt = idx - z*154;
    int r0 = mt*64;
    const float* w0 = z ? te0 : se0;
    const float* b0 = z ? teb0 : seb0;
    __hip_bfloat16* H = z ? hA_te : hA_se;
    float* sw = (float*)smem;          // 4608
    float* sb = sw + 4608;             // 384
    float* sx = sb + 384;              // 768
    for (int i = tid; i < 4608; i += 256) sw[i] = w0[i];
    for (int i = tid; i < 384; i += 256) sb[i] = b0[i];
    for (int v = tid; v < 768; v += 256) {
      int r = v / 12, t = v - r*12;
      int row = r0 + r;
      float xv = 0.f;
      if (row < NROWS) {
        int b = row / GDIM, g = row - b*GDIM;
        xv = inp[b*IN_B + (1+t)*IN_ROW + 2 + g];
      }
      sx[v] = xv;
    }
    __syncthreads();
    for (int c = tid; c < 384; c += 256) {
      float wv[12];
      #pragma unroll
      for (int t = 0; t < 12; t++) wv[t] = sw[t*384 + c];
      float bv = sb[c];
      for (int r = 0; r < 64; r++) {
        int row = r0 + r;
        if (row >= NROWS) break;
        float acc = bv;
        #pragma unroll
        for (int t = 0; t < 12; t++) acc += sx[r*12+t] * wv[t];
        H[(size_t)row*384 + c] = __float2bfloat16(fmaxf(acc, 0.f));
      }
    }
  } else {
    int s = bid - 692;
    int q = s / 36, u = s % 36;
    tr_tile(q ? te1 : se1, q ? Wte1 : Wse1, 384, 384, 384, 384, u % 6, u / 6, smem, tid);
  }
}

// ============ F2: L1 GEMM se/te [0,924, XCD-swz) + tr-rest [924,1784) + xln [1784,3032, XCD-swz)
__global__ __launch_bounds__(256) void k_f2(
    const __hip_bfloat16* __restrict__ hA_se, const __hip_bfloat16* __restrict__ hA_te,
    const __hip_bfloat16* __restrict__ Wse1, const __hip_bfloat16* __restrict__ Wte1,
    const float* __restrict__ seb1, const float* __restrict__ teb1,
    __hip_bfloat16* __restrict__ hB_se, __hip_bfloat16* __restrict__ hB_te,
    const float* __restrict__ inp, const float* __restrict__ dbs,
    const float* __restrict__ A_pre, const float* __restrict__ Cp,
    const float* __restrict__ gamma, const float* __restrict__ beta,
    __hip_bfloat16* __restrict__ xlnT, __hip_bfloat16* __restrict__ xg,
    const float* se2, const float* te2, const float* se3, const float* te3,
    const float* g2g, const float* tgw,
    __hip_bfloat16* Wse2, __hip_bfloat16* Wte2, __hip_bfloat16* Wse3,
    __hip_bfloat16* Wte3, __hip_bfloat16* Wgt, __hip_bfloat16* Wtg) {
  __shared__ alignas(16) char smem[32640];
  int bid = blockIdx.x, tid = threadIdx.x;
  if (bid < 924) {
    int s = xcd_swz(bid, 924);           // same-m blocks -> same XCD (A reuse in L2)
    int z = s / 462, rem = s - z*462;
    mgemm_body(z ? hA_te : hA_se, 384, z ? Wte1 : Wse1, 384,
               z ? teb1 : seb1, z ? hB_te : hB_se, 384, 0,
               NROWS, 384, 0, 6, 0, 1, smem, (rem/6)*128, (rem%6)*64);
  } else if (bid < 1784) {
    int s = bid - 924;
    if (s < 770) {
      tr_tile(tgw, Wtg, 9824, 307, 320, 9856, s % 154, s / 154, smem, tid);
    } else if (s < 842) {
      int q = (s-770) / 36, u = (s-770) % 36;
      tr_tile(q ? te2 : se2, q ? Wte2 : Wse2, 384, 384, 384, 384, u % 6, u / 6, smem, tid);
    } else {
      int q = (s-842) / 6, u = (s-842) % 6;
      const float* src = q==0?se3 : q==1?te3 : g2g;
      __hip_bfloat16* dst = q==0?Wse3 : q==1?Wte3 : Wgt;
      tr_tile(src, dst, 384, 12, 64, 384, u, 0, smem, tid);
    }
  } else {
    // xln: 8 g per block; 32 b x 39 chunks. XCD-swz: each b's 39 chunks co-locate
    // on one XCD so its 37 KB A_pre/Cp panel is fetched into one L2, not eight.
    // (range offset 1784 % 8 == 0, so (bid-1784)&7 is the real XCD index)
    int idx = xcd_swz(bid - 1784, 1248);
    int b = idx / 39, gc = idx - b*39;
    int g0 = gc*8, ng = min(8, GDIM - g0);
    float* sA  = (float*)smem;          // 4608
    float* sxb = sA + 4608;             // 3072 (8x384)
    float* sCs = sxb + 3072;            // 384
    float* sx3 = sCs + 384;             // 96
    int date = (int)inp[b*IN_B + 1];
    for (int v = tid; v < 4608; v += 256) sA[v] = A_pre[b*4608 + v];
    for (int e = tid; e < 384; e += 256) {
      float s = 0.f;
      #pragma unroll
      for (int t = 0; t < 12; t++) s += Cp[b*4608 + t*384 + e];
      sCs[e] = s;
    }
    if (tid < ng*12) {
      int gl = tid / 12, t = tid - gl*12;
      sx3[tid] = inp[b*IN_B + (1+t)*IN_ROW + 2 + g0 + gl];
    }
    if (gc == 38) {
      for (int v = tid; v < 384; v += 256) {
        int j = v >> 5, c = v & 31;
        xlnT[(size_t)(b*12+j)*9856 + 9824 + c] = __float2bfloat16(0.f);
      }
    }
    __syncthreads();
    for (int o = tid; o < ng*384; o += 256) {
      int gl = o / 384, e = o - gl*384;
      float acc = sCs[e] + dbs[(size_t)date*117888 + (g0+gl)*384 + e];
      #pragma unroll
      for (int t = 0; t < 12; t++) acc += sx3[gl*12+t] * sA[t*384 + e];
      sxb[gl*384 + e] = acc;
    }
    __syncthreads();
    if (tid < ng*32) {
      int gl = tid >> 5, i = tid & 31;
      const float* xb = sxb + gl*384 + i*12;
      float m = 0.f;
      #pragma unroll
      for (int q = 0; q < 12; q++) m += xb[q];
      m *= (1.f/12.f);
      float v = 0.f;
      #pragma unroll
      for (int q = 0; q < 12; q++) { float d = xb[q] - m; v += d*d; }
      v *= (1.f/12.f);
      float rs = rsqrtf(v + 1e-3f);
      int g = g0 + gl;
      #pragma unroll
      for (int j = 0; j < 12; j++) {
        float y = (xb[j] - m) * rs * gamma[j] + beta[j];
        y = (y >= 0.f) ? y : 0.3f*y;
        __hip_bfloat16 yb = __float2bfloat16(y);
        xlnT[(size_t)(b*12 + j)*9856 + g*32 + i] = yb;
        int q2 = j*GDIM + g;
        int gq = q2 / 12, tq = q2 - gq*12;
        xg[(size_t)(b*GDIM + gq)*384 + tq*32 + i] = yb;
      }
    }
  }
}

// ============ F3: L2 GEMM se/te [0,924, XCD-swz) + tg splitK [924,1164, XCD-swz) + gt [1164,1241)
__global__ __launch_bounds__(256) void k_f3(
    const __hip_bfloat16* __restrict__ hB_se, const __hip_bfloat16* __restrict__ hB_te,
    const __hip_bfloat16* __restrict__ Wse2, const __hip_bfloat16* __restrict__ Wte2,
    const float* __restrict__ seb2, const float* __restrict__ teb2,
    __hip_bfloat16* __restrict__ hA_se, __hip_bfloat16* __restrict__ hA_te,
    const __hip_bfloat16* __restrict__ xlnT, const __hip_bfloat16* __restrict__ Wtg,
    float* __restrict__ tgp,
    const __hip_bfloat16* __restrict__ xg, const __hip_bfloat16* __restrict__ Wgt,
    float* __restrict__ gtv) {
  __shared__ alignas(16) char smem[24576];
  int bid = blockIdx.x;
  if (bid < 924) {
    int s = xcd_swz(bid, 924);
    int z = s / 462, rem = s - z*462;
    mgemm_body(z ? hB_te : hB_se, 384, z ? Wte2 : Wse2, 384,
               z ? teb2 : seb2, z ? hA_te : hA_se, 384, 0,
               NROWS, 384, 0, 6, 1, 1, smem, (rem/6)*128, (rem%6)*64);
  } else if (bid < 1164) {
    int s = xcd_swz(bid - 924, 240);     // same-(z,m) blocks -> same XCD (xlnT reuse)
    int z = s / 15, rem = s - z*15;
    int n0 = (rem % 5)*64, m0 = (rem / 5)*128;
    int kt0 = z*10, kt1 = min(154, kt0 + 10);
    mgemm_body(xlnT, 9856, Wtg, 9856, nullptr, tgp, 320, (long)z*122880,
               384, 320, kt0, kt1, 0, 0, smem, m0, n0);
  } else {
    int m0 = (bid - 1164)*128;
    mgemm_body(xg, 384, Wgt, 384, nullptr, gtv, 12, 0,
               NROWS, 12, 0, 6, 0, 0, smem, m0, 0);
  }
}

// ============ F4: L3 GEMM se/te [0,154) + tgred [154,274)
__global__ __launch_bounds__(256) void k_f4(
    const __hip_bfloat16* __restrict__ hA_se, const __hip_bfloat16* __restrict__ hA_te,
    const __hip_bfloat16* __restrict__ Wse3, const __hip_bfloat16* __restrict__ Wte3,
    const float* __restrict__ seb3, const float* __restrict__ teb3,
    float* __restrict__ x1, float* __restrict__ x2,
    const float* __restrict__ tgp, float* __restrict__ tgv) {
  __shared__ alignas(16) char smem[24576];
  int bid = blockIdx.x;
  if (bid < 154) {
    int z = bid / 77, m0 = (bid - z*77)*128;
    mgemm_body(z ? hA_te : hA_se, 384, z ? Wte3 : Wse3, 384,
               z ? teb3 : seb3, z ? x2 : x1, 12, 0,
               NROWS, 12, 0, 6, 0, 0, smem, m0, 0);
  } else {
    int base = (bid - 154) * 1024;
    #pragma unroll
    for (int q = 0; q < 4; q++) {
      int gid = base + q*256 + threadIdx.x;
      float s = 0.f;
      #pragma unroll
      for (int z = 0; z < 16; z++) s += tgp[(size_t)z*122880 + gid];
      tgv[gid] = s;
    }
  }
}

// ============ F5: gates + fully_w + scale
__global__ __launch_bounds__(256) void k_final(const float* __restrict__ tgv,
    const float* __restrict__ gt, const float* __restrict__ x1,
    const float* __restrict__ x2, const float* __restrict__ fw,
    float* __restrict__ out) {
  __shared__ float w[288];
  for (int idx = threadIdx.x; idx < 288; idx += 256) w[idx] = fw[idx];
  __syncthreads();
  int gid = blockIdx.x*256 + threadIdx.x;
  if (gid >= NROWS) return;
  int b = gid / GDIM, g = gid - b*GDIM;
  float g1[12], g2[12];
  #pragma unroll
  for (int n = 0; n < 12; n++) {
    float tv  = tgv[(size_t)(b*12+n)*320 + g];
    float x1v = x1[(size_t)gid*12 + n];
    float gv  = gt[(size_t)gid*12 + n];
    float x2v = x2[(size_t)gid*12 + n];
    float s1 = 1.f/(1.f + __expf(-tv));
    float s2 = 1.f/(1.f + __expf(-gv));
    g1[n] = (tv + x1v)*s1;
    g2[n] = (gv + x2v)*s2;
  }
  #pragma unroll
  for (int o = 0; o < 12; o++) {
    float acc = 0.f;
    #pragma unroll
    for (int n = 0; n < 12; n++)
      acc += g1[n]*w[n*12+o] + g2[n]*w[(12+n)*12+o];
    out[(size_t)(b*12+o)*GDIM + g] = acc*50.f + 60.f;
  }
}

extern "C" void kernel_launch(void* const* d_in, const int* in_sizes, int n_in,
                              void* d_out, int out_size, void* d_ws, size_t ws_size,
                              hipStream_t stream) {
  const float* inp    = (const float*)d_in[0];
  const float* cw     = (const float*)d_in[1];
  const float* cb     = (const float*)d_in[2];
  const float* dws    = (const float*)d_in[3];
  const float* dbs    = (const float*)d_in[4];
  const float* ln_g   = (const float*)d_in[5];
  const float* ln_b   = (const float*)d_in[6];
  const float* tge2tg = (const float*)d_in[7];
  const float* gte2gt = (const float*)d_in[8];
  const float* fullyw = (const float*)d_in[9];
  const float* se[8];
  const float* te[8];
  for (int i = 0; i < 8; i++) { se[i] = (const float*)d_in[10+i]; te[i] = (const float*)d_in[18+i]; }
  float* out = (float*)d_out;

  // ---- workspace carve (~64 MB, no aliasing) ----
  char* base = (char*)d_ws;
  size_t off = 0;
  auto alloc = [&](size_t bytes) { char* r = base + off; off += (bytes + 255) & ~(size_t)255; return r; };
  float* A_pre = (float*)alloc(147456*4);
  float* Cp    = (float*)alloc(147456*4);
  float* x1    = (float*)alloc(117888*4);
  float* x2    = (float*)alloc(117888*4);
  float* gtv   = (float*)alloc(117888*4);
  float* tgv   = (float*)alloc(122880*4);
  float* tgp   = (float*)alloc((size_t)16*122880*4);
  __hip_bfloat16* hA_se = (__hip_bfloat16*)alloc((size_t)MPAD*384*2);
  __hip_bfloat16* hA_te = (__hip_bfloat16*)alloc((size_t)MPAD*384*2);
  __hip_bfloat16* hB_se = (__hip_bfloat16*)alloc((size_t)MPAD*384*2);
  __hip_bfloat16* hB_te = (__hip_bfloat16*)alloc((size_t)MPAD*384*2);
  __hip_bfloat16* xlnT  = (__hip_bfloat16*)alloc((size_t)384*9856*2);
  __hip_bfloat16* xg    = (__hip_bfloat16*)alloc((size_t)MPAD*384*2);
  __hip_bfloat16* Wse1 = (__hip_bfloat16*)alloc(147456*2);
  __hip_bfloat16* Wse2 = (__hip_bfloat16*)alloc(147456*2);
  __hip_bfloat16* Wte1 = (__hip_bfloat16*)alloc(147456*2);
  __hip_bfloat16* Wte2 = (__hip_bfloat16*)alloc(147456*2);
  __hip_bfloat16* Wse3 = (__hip_bfloat16*)alloc(24576*2);
  __hip_bfloat16* Wte3 = (__hip_bfloat16*)alloc(24576*2);
  __hip_bfloat16* Wgt  = (__hip_bfloat16*)alloc(24576*2);
  __hip_bfloat16* Wtg  = (__hip_bfloat16*)alloc((size_t)320*9856*2);

  // F1: prep + layer-0 + Wse1/Wte1 transposes (critical path for F2 only)
  k_f1<<<764, 256, 0, stream>>>(inp, dws, cw, cb, A_pre, Cp,
      se[2], te[2], Wse1, Wte1,
      se[0], se[1], te[0], te[1], hA_se, hA_te);

  // F2: L1 GEMMs (XCD-swz) + remaining transposes + xln (XCD-swz)
  k_f2<<<3032, 256, 0, stream>>>(hA_se, hA_te, Wse1, Wte1, se[3], te[3],
      hB_se, hB_te, inp, dbs, A_pre, Cp, ln_g, ln_b, xlnT, xg,
      se[4], te[4], se[6], te[6], gte2gt, tge2tg,
      Wse2, Wte2, Wse3, Wte3, Wgt, Wtg);

  // F3: L2 GEMMs (XCD-swz) + tg split-K (XCD-swz) + gt
  k_f3<<<1241, 256, 0, stream>>>(hB_se, hB_te, Wse2, Wte2, se[5], te[5],
      hA_se, hA_te, xlnT, Wtg, tgp, xg, Wgt, gtv);

  // F4: L3 GEMMs + tg partial reduction
  k_f4<<<274, 256, 0, stream>>>(hA_se, hA_te, Wse3, Wte3, se[7], te[7], x1, x2, tgp, tgv);

  // F5: gates + output
  k_final<<<39, 256, 0, stream>>>(tgv, gtv, x1, x2, fullyw, out);
}